// Round 1
// baseline (8875.545 us; speedup 1.0000x reference)
//
#include <hip/hip_runtime.h>
#include <hip/hip_bf16.h>
#include <stdint.h>

#define CRF_B 128
#define CRF_T 256
#define CRF_K 600
#define FWD_NT 320   // 5 waves, 2 columns per thread (covers 600 cols)

// ---------------- prep: expT[i,j] = bf16(exp(trans[i,j])) ----------------
__global__ __launch_bounds__(256) void prep_kernel(const float* __restrict__ trans,
                                                   uint16_t* __restrict__ expT)
{
    int idx = blockIdx.x * 256 + threadIdx.x;
    if (idx < CRF_K * CRF_K) {
        float e = __expf(trans[idx]);
        uint32_t u = __float_as_uint(e);
        u += 0x7fffu + ((u >> 16) & 1u);   // RNE to bf16
        expT[idx] = (uint16_t)(u >> 16);
    }
}

// ---------------- gold-path score: unary + binary ----------------
__global__ __launch_bounds__(64) void score_kernel(const float* __restrict__ pot,
                                                   const float* __restrict__ trans,
                                                   const int* __restrict__ tags,
                                                   const int* __restrict__ seq_len,
                                                   float* __restrict__ scoreArr)
{
    int b = blockIdx.x;
    int lane = threadIdx.x;
    int L = seq_len[b];
    float s = 0.f;
    for (int t = lane; t < CRF_T; t += 64) {
        if (t < L) {
            int tg = tags[b * CRF_T + t];
            s += pot[((size_t)b * CRF_T + t) * CRF_K + tg];
            if (t >= 1) {
                int tp = tags[b * CRF_T + t - 1];
                s += trans[tp * CRF_K + tg];
            }
        }
    }
    for (int o = 32; o; o >>= 1) s += __shfl_down(s, o);
    if (lane == 0) scoreArr[b] = s;
}

// ---------------- fused forward: scaled-exp lognorm + exact-f32 viterbi ----------------
__global__ __launch_bounds__(FWD_NT) void fwd_kernel(
    const float* __restrict__ pot,
    const float* __restrict__ trans,
    const uint16_t* __restrict__ expT,
    const int* __restrict__ seq_len,
    uint16_t* __restrict__ bp,
    float* __restrict__ lognormArr,
    int* __restrict__ lastArr)
{
    const int b   = blockIdx.x;
    const int tid = threadIdx.x;
    const bool active = (tid * 2) < CRF_K;
    const int j0 = active ? tid * 2 : 0;
    const int L  = seq_len[b];
    const int lane = tid & 63;
    const int wid  = tid >> 6;
    constexpr int NW = FWD_NT / 64;

    __shared__ __align__(16) float aexp[CRF_K];
    __shared__ __align__(16) float aV[CRF_K];
    __shared__ float red[NW];
    __shared__ int   redi[NW];
    __shared__ float bcast;

    const float* pb = pot + (size_t)b * CRF_T * CRF_K;

    // ---- init (t = 0): alpha0 = potentials[b,0,:] ----
    float2 p0 = *(const float2*)(pb + j0);
    {
        float x = active ? fmaxf(p0.x, p0.y) : -INFINITY;
        for (int o = 32; o; o >>= 1) x = fmaxf(x, __shfl_down(x, o));
        if (lane == 0) red[wid] = x;
        __syncthreads();
        if (tid == 0) { float m = red[0]; for (int w = 1; w < NW; ++w) m = fmaxf(m, red[w]); bcast = m; }
        __syncthreads();
    }
    float m0 = bcast;
    float logscale = m0;   // only thread 0's copy is ultimately used
    if (active) {
        aexp[j0]     = __expf(p0.x - m0);
        aexp[j0 + 1] = __expf(p0.y - m0);
        aV[j0]     = p0.x;
        aV[j0 + 1] = p0.y;
    }
    __syncthreads();

    // ---- recursion t = 1 .. L-1 ----
    for (int t = 1; t < L; ++t) {
        float sx = 0.f, sy = 0.f;
        float vx = -INFINITY, vy = -INFINITY;
        int bx = 0, by = 0;
        const float*    tp = trans + j0;
        const uint16_t* ep = expT  + j0;

        for (int i = 0; i < CRF_K; i += 4) {
            float4 a4 = *(const float4*)(aexp + i);
            float4 w4 = *(const float4*)(aV + i);
            float2 t0 = *(const float2*)(tp + (i + 0) * CRF_K);
            float2 t1 = *(const float2*)(tp + (i + 1) * CRF_K);
            float2 t2 = *(const float2*)(tp + (i + 2) * CRF_K);
            float2 t3 = *(const float2*)(tp + (i + 3) * CRF_K);
            uint32_t e0 = *(const uint32_t*)(ep + (i + 0) * CRF_K);
            uint32_t e1 = *(const uint32_t*)(ep + (i + 1) * CRF_K);
            uint32_t e2 = *(const uint32_t*)(ep + (i + 2) * CRF_K);
            uint32_t e3 = *(const uint32_t*)(ep + (i + 3) * CRF_K);

            sx = fmaf(a4.x, __uint_as_float(e0 << 16), sx);
            sy = fmaf(a4.x, __uint_as_float(e0 & 0xffff0000u), sy);
            { float cx = w4.x + t0.x; if (cx > vx) { vx = cx; bx = i + 0; }
              float cy = w4.x + t0.y; if (cy > vy) { vy = cy; by = i + 0; } }

            sx = fmaf(a4.y, __uint_as_float(e1 << 16), sx);
            sy = fmaf(a4.y, __uint_as_float(e1 & 0xffff0000u), sy);
            { float cx = w4.y + t1.x; if (cx > vx) { vx = cx; bx = i + 1; }
              float cy = w4.y + t1.y; if (cy > vy) { vy = cy; by = i + 1; } }

            sx = fmaf(a4.z, __uint_as_float(e2 << 16), sx);
            sy = fmaf(a4.z, __uint_as_float(e2 & 0xffff0000u), sy);
            { float cx = w4.z + t2.x; if (cx > vx) { vx = cx; bx = i + 2; }
              float cy = w4.z + t2.y; if (cy > vy) { vy = cy; by = i + 2; } }

            sx = fmaf(a4.w, __uint_as_float(e3 << 16), sx);
            sy = fmaf(a4.w, __uint_as_float(e3 & 0xffff0000u), sy);
            { float cx = w4.w + t3.x; if (cx > vx) { vx = cx; bx = i + 3; }
              float cy = w4.w + t3.y; if (cy > vy) { vy = cy; by = i + 3; } }
        }

        float2 em = *(const float2*)(pb + (size_t)t * CRF_K + j0);
        float rx  = sx * __expf(em.x);
        float ry  = sy * __expf(em.y);
        float vnx = vx + em.x;
        float vny = vy + em.y;

        if (active) {
            uint32_t packed = (uint32_t)bx | ((uint32_t)by << 16);
            *(uint32_t*)(bp + ((size_t)b * (CRF_T - 1) + (t - 1)) * CRF_K + j0) = packed;
        }

        // per-step rescale: m = max_j r[j]
        float mm = active ? fmaxf(rx, ry) : 0.f;
        for (int o = 32; o; o >>= 1) mm = fmaxf(mm, __shfl_down(mm, o));
        if (lane == 0) red[wid] = mm;
        __syncthreads();
        if (tid == 0) { float m = red[0]; for (int w = 1; w < NW; ++w) m = fmaxf(m, red[w]); bcast = m; }
        __syncthreads();
        float m = bcast;
        float inv = 1.0f / m;
        if (tid == 0) logscale += __logf(m);
        if (active) {
            aexp[j0]     = rx * inv;
            aexp[j0 + 1] = ry * inv;
            aV[j0]     = vnx;
            aV[j0 + 1] = vny;
        }
        __syncthreads();
    }

    // ---- finalize lognorm: logscale + log(sum aexp) ----
    float ss = active ? (aexp[j0] + aexp[j0 + 1]) : 0.f;
    for (int o = 32; o; o >>= 1) ss += __shfl_down(ss, o);
    if (lane == 0) red[wid] = ss;
    __syncthreads();
    if (tid == 0) { float s = 0.f; for (int w = 0; w < NW; ++w) s += red[w]; bcast = s; }
    __syncthreads();
    float totalexp = bcast;

    // ---- finalize viterbi: last = argmax_j aV[j] (first-max tie-break) ----
    float fv = active ? fmaxf(aV[j0], aV[j0 + 1]) : -INFINITY;
    float y = fv;
    for (int o = 32; o; o >>= 1) y = fmaxf(y, __shfl_down(y, o));
    if (lane == 0) red[wid] = y;
    __syncthreads();
    if (tid == 0) { float m = red[0]; for (int w = 1; w < NW; ++w) m = fmaxf(m, red[w]); bcast = m; }
    __syncthreads();
    float vmax = bcast;
    int cand = 0x7fffffff;
    if (active) {
        if (aV[j0] == vmax)          cand = j0;
        else if (aV[j0 + 1] == vmax) cand = j0 + 1;
    }
    int c = cand;
    for (int o = 32; o; o >>= 1) c = min(c, __shfl_down(c, o));
    if (lane == 0) redi[wid] = c;
    __syncthreads();
    if (tid == 0) {
        int mi = redi[0];
        for (int w = 1; w < NW; ++w) mi = min(mi, redi[w]);
        lastArr[b] = mi;
        lognormArr[b] = logscale + __logf(totalexp);
    }
}

// ---------------- backtrace ----------------
__global__ __launch_bounds__(64) void backtrace_kernel(const uint16_t* __restrict__ bp,
                                                       const int* __restrict__ seq_len,
                                                       const int* __restrict__ lastArr,
                                                       float* __restrict__ out)
{
    int r = blockIdx.x * 64 + threadIdx.x;
    if (r >= CRF_B) return;
    int L = seq_len[r];
    float* o = out + 1 + (size_t)r * CRF_T;
    int tag = lastArr[r];
    for (int t = CRF_T - 1; t >= L; --t) o[t] = 0.f;
    o[L - 1] = (float)tag;
    for (int t = L - 2; t >= 0; --t) {
        tag = bp[((size_t)r * (CRF_T - 1) + t) * CRF_K + tag];
        o[t] = (float)tag;
    }
}

// ---------------- loss = -mean(score - lognorm) ----------------
__global__ __launch_bounds__(128) void loss_kernel(const float* __restrict__ scoreArr,
                                                   const float* __restrict__ lognormArr,
                                                   float* __restrict__ out)
{
    int tid = threadIdx.x;
    float x = scoreArr[tid] - lognormArr[tid];
    for (int o = 32; o; o >>= 1) x += __shfl_down(x, o);
    __shared__ float r2[2];
    if ((tid & 63) == 0) r2[tid >> 6] = x;
    __syncthreads();
    if (tid == 0) out[0] = -(r2[0] + r2[1]) / (float)CRF_B;
}

extern "C" void kernel_launch(void* const* d_in, const int* in_sizes, int n_in,
                              void* d_out, int out_size, void* d_ws, size_t ws_size,
                              hipStream_t stream)
{
    const float* pot     = (const float*)d_in[0];
    const float* trans   = (const float*)d_in[1];
    const int*   tags    = (const int*)d_in[2];
    const int*   seq_len = (const int*)d_in[3];
    float* out = (float*)d_out;

    char* ws = (char*)d_ws;
    const size_t bpBytes = (size_t)CRF_B * (CRF_T - 1) * CRF_K * 2;      // 39,168,000
    uint16_t* bp   = (uint16_t*)ws;
    uint16_t* expT = (uint16_t*)(ws + bpBytes);                          // 720,000 B
    float* scoreArr   = (float*)(ws + bpBytes + (size_t)CRF_K * CRF_K * 2);
    float* lognormArr = scoreArr + CRF_B;
    int*   lastArr    = (int*)(lognormArr + CRF_B);

    prep_kernel<<<(CRF_K * CRF_K + 255) / 256, 256, 0, stream>>>(trans, expT);
    score_kernel<<<CRF_B, 64, 0, stream>>>(pot, trans, tags, seq_len, scoreArr);
    fwd_kernel<<<CRF_B, FWD_NT, 0, stream>>>(pot, trans, expT, seq_len, bp, lognormArr, lastArr);
    backtrace_kernel<<<(CRF_B + 63) / 64, 64, 0, stream>>>(bp, seq_len, lastArr, out);
    loss_kernel<<<1, 128, 0, stream>>>(scoreArr, lognormArr, out);
}

// Round 3
// 4330.862 us; speedup vs baseline: 2.0494x; 2.0494x over previous
//
#include <hip/hip_runtime.h>
#include <stdint.h>

#define CRF_B 128
#define CRF_T 256
#define CRF_K 600
#define FWD_NT 640          // 10 waves
#define NG 4                // i-groups
#define ROWS 150            // rows per i-group (NG*ROWS = CRF_K)
#define NWAVE (FWD_NT / 64)

// ---------------- prep: expT[i,j] = bf16(exp(trans[i,j])) ----------------
__global__ __launch_bounds__(256) void prep_kernel(const float* __restrict__ trans,
                                                   uint16_t* __restrict__ expT)
{
    int idx = blockIdx.x * 256 + threadIdx.x;
    if (idx < CRF_K * CRF_K) {
        float e = __expf(trans[idx]);
        uint32_t u = __float_as_uint(e);
        u += 0x7fffu + ((u >> 16) & 1u);   // RNE to bf16
        expT[idx] = (uint16_t)(u >> 16);
    }
}

// ---------------- gold-path score: unary + binary ----------------
__global__ __launch_bounds__(64) void score_kernel(const float* __restrict__ pot,
                                                   const float* __restrict__ trans,
                                                   const int* __restrict__ tags,
                                                   const int* __restrict__ seq_len,
                                                   float* __restrict__ scoreArr)
{
    int b = blockIdx.x;
    int lane = threadIdx.x;
    int L = seq_len[b];
    float s = 0.f;
    for (int t = lane; t < CRF_T; t += 64) {
        if (t < L) {
            int tg = tags[b * CRF_T + t];
            s += pot[((size_t)b * CRF_T + t) * CRF_K + tg];
            if (t >= 1) {
                int tp = tags[b * CRF_T + t - 1];
                s += trans[tp * CRF_K + tg];
            }
        }
    }
    for (int o = 32; o; o >>= 1) s += __shfl_down(s, o);
    if (lane == 0) scoreArr[b] = s;
}

// ---------------- fused forward, role-split across 256 blocks ----------------
// bid < 128  : Viterbi role (exact f32 max-plus + backpointers)
// bid >= 128 : lognorm role (scaled-exp forward with bf16 expT)
__global__ __launch_bounds__(FWD_NT) void fwd_kernel(
    const float* __restrict__ pot,
    const float* __restrict__ trans,
    const uint16_t* __restrict__ expT,
    const int* __restrict__ seq_len,
    uint16_t* __restrict__ bp,
    float* __restrict__ lognormArr,
    int* __restrict__ lastArr)
{
    const int bid = blockIdx.x;
    const bool isVit = bid < CRF_B;
    const int b   = isVit ? bid : bid - CRF_B;
    const int tid = threadIdx.x;
    const int lane = tid & 63;
    const int wid  = tid >> 6;
    const int L = seq_len[b];

    const bool act  = tid < NG * ROWS;       // 600 worker threads for partial phase
    const bool jact = tid < CRF_K;           // 600 threads for combine phase
    const int c  = tid % ROWS;               // column group 0..149
    const int g  = tid / ROWS;               // i-group 0..3 (g==4 -> idle)
    const int j0 = 4 * c;
    const int i0 = ROWS * g;

    __shared__ __align__(16) float sAlpha[CRF_K];
    __shared__ __align__(16) float sPart[NG * CRF_K];
    __shared__ __align__(16) int   sPartB[NG * CRF_K];
    __shared__ float sRed[NWAVE];
    __shared__ int   sRedI[NWAVE];
    __shared__ float sB;

    const float* pb = pot + (size_t)b * CRF_T * CRF_K;

    if (isVit) {
        // ================= Viterbi role =================
        if (jact) sAlpha[tid] = pb[tid];
        __syncthreads();

        for (int t = 1; t < L; ++t) {
            float v0 = -INFINITY, v1 = -INFINITY, v2 = -INFINITY, v3 = -INFINITY;
            int   b0 = 0, b1 = 0, b2 = 0, b3 = 0;
            if (act) {
                const float* trow = trans + (size_t)i0 * CRF_K + j0;
                #pragma unroll 5
                for (int ii = 0; ii < ROWS; ii += 2) {
                    float2 a2  = *(const float2*)(sAlpha + i0 + ii);
                    float4 tr0 = *(const float4*)(trow);
                    float4 tr1 = *(const float4*)(trow + CRF_K);
                    trow += 2 * CRF_K;
                    int ic0 = i0 + ii, ic1 = i0 + ii + 1;
                    float c0, c1, c2, c3;
                    c0 = a2.x + tr0.x; c1 = a2.x + tr0.y; c2 = a2.x + tr0.z; c3 = a2.x + tr0.w;
                    b0 = (c0 > v0) ? ic0 : b0; v0 = fmaxf(v0, c0);
                    b1 = (c1 > v1) ? ic0 : b1; v1 = fmaxf(v1, c1);
                    b2 = (c2 > v2) ? ic0 : b2; v2 = fmaxf(v2, c2);
                    b3 = (c3 > v3) ? ic0 : b3; v3 = fmaxf(v3, c3);
                    c0 = a2.y + tr1.x; c1 = a2.y + tr1.y; c2 = a2.y + tr1.z; c3 = a2.y + tr1.w;
                    b0 = (c0 > v0) ? ic1 : b0; v0 = fmaxf(v0, c0);
                    b1 = (c1 > v1) ? ic1 : b1; v1 = fmaxf(v1, c1);
                    b2 = (c2 > v2) ? ic1 : b2; v2 = fmaxf(v2, c2);
                    b3 = (c3 > v3) ? ic1 : b3; v3 = fmaxf(v3, c3);
                }
                float4 pv = {v0, v1, v2, v3};
                int4   pi = {b0, b1, b2, b3};
                *(float4*)(sPart  + g * CRF_K + j0) = pv;
                *(int4*)  (sPartB + g * CRF_K + j0) = pi;
            }
            __syncthreads();
            if (jact) {
                const int j = tid;
                float v  = sPart[j];
                int   ix = sPartB[j];
                #pragma unroll
                for (int gg = 1; gg < NG; ++gg) {
                    float vg = sPart[gg * CRF_K + j];
                    int   ig = sPartB[gg * CRF_K + j];
                    ix = (vg > v) ? ig : ix;     // ascending group, strict > => first-max
                    v  = fmaxf(v, vg);
                }
                bp[((size_t)b * (CRF_T - 1) + (t - 1)) * CRF_K + j] = (uint16_t)ix;
                sAlpha[j] = v + pb[(size_t)t * CRF_K + j];
            }
            __syncthreads();
        }

        // finalize: last = argmax_j sAlpha[j], first-max tie-break
        float mv = jact ? sAlpha[tid] : -INFINITY;
        float y = mv;
        for (int o = 32; o; o >>= 1) y = fmaxf(y, __shfl_down(y, o));
        if (lane == 0) sRed[wid] = y;
        __syncthreads();
        if (tid == 0) { float m = sRed[0]; for (int w = 1; w < NWAVE; ++w) m = fmaxf(m, sRed[w]); sB = m; }
        __syncthreads();
        float vmax = sB;
        int cand = (jact && mv == vmax) ? tid : 0x7fffffff;
        for (int o = 32; o; o >>= 1) cand = min(cand, __shfl_down(cand, o));
        if (lane == 0) sRedI[wid] = cand;
        __syncthreads();
        if (tid == 0) {
            int mi = sRedI[0];
            for (int w = 1; w < NWAVE; ++w) mi = min(mi, sRedI[w]);
            lastArr[b] = mi;
        }
    } else {
        // ================= lognorm role =================
        float logscale = 0.f;
        float p0 = jact ? pb[tid] : -INFINITY;
        {
            float x = p0;
            for (int o = 32; o; o >>= 1) x = fmaxf(x, __shfl_down(x, o));
            if (lane == 0) sRed[wid] = x;
            __syncthreads();
            if (tid == 0) { float m = sRed[0]; for (int w = 1; w < NWAVE; ++w) m = fmaxf(m, sRed[w]); sB = m; }
            __syncthreads();
        }
        float m0 = sB;
        logscale = m0;
        if (jact) sAlpha[tid] = __expf(p0 - m0);
        __syncthreads();

        for (int t = 1; t < L; ++t) {
            float s0 = 0.f, s1 = 0.f, s2 = 0.f, s3 = 0.f;
            if (act) {
                const uint16_t* erow = expT + (size_t)i0 * CRF_K + j0;
                #pragma unroll 5
                for (int ii = 0; ii < ROWS; ii += 2) {
                    float2 a2 = *(const float2*)(sAlpha + i0 + ii);
                    uint2 ua = *(const uint2*)(erow);
                    uint2 ub = *(const uint2*)(erow + CRF_K);
                    erow += 2 * CRF_K;
                    s0 = fmaf(a2.x, __uint_as_float(ua.x << 16),          s0);
                    s1 = fmaf(a2.x, __uint_as_float(ua.x & 0xffff0000u),  s1);
                    s2 = fmaf(a2.x, __uint_as_float(ua.y << 16),          s2);
                    s3 = fmaf(a2.x, __uint_as_float(ua.y & 0xffff0000u),  s3);
                    s0 = fmaf(a2.y, __uint_as_float(ub.x << 16),          s0);
                    s1 = fmaf(a2.y, __uint_as_float(ub.x & 0xffff0000u),  s1);
                    s2 = fmaf(a2.y, __uint_as_float(ub.y << 16),          s2);
                    s3 = fmaf(a2.y, __uint_as_float(ub.y & 0xffff0000u),  s3);
                }
                float4 ps = {s0, s1, s2, s3};
                *(float4*)(sPart + g * CRF_K + j0) = ps;
            }
            __syncthreads();
            float r = 0.f;
            if (jact) {
                const int j = tid;
                r = ((sPart[j] + sPart[CRF_K + j]) + (sPart[2 * CRF_K + j] + sPart[3 * CRF_K + j]))
                    * __expf(pb[(size_t)t * CRF_K + j]);
            }
            float mm = r;   // r >= 0 so 0 is a valid identity for idle lanes
            for (int o = 32; o; o >>= 1) mm = fmaxf(mm, __shfl_down(mm, o));
            if (lane == 0) sRed[wid] = mm;
            __syncthreads();
            if (tid == 0) { float mx = sRed[0]; for (int w = 1; w < NWAVE; ++w) mx = fmaxf(mx, sRed[w]); sB = mx; }
            __syncthreads();
            float mx = sB;
            if (tid == 0) logscale += __logf(mx);
            if (jact) sAlpha[tid] = r * (1.0f / mx);
            __syncthreads();
        }

        // finalize lognorm = logscale + log(sum aexp)
        float ss = jact ? sAlpha[tid] : 0.f;
        for (int o = 32; o; o >>= 1) ss += __shfl_down(ss, o);
        if (lane == 0) sRed[wid] = ss;
        __syncthreads();
        if (tid == 0) {
            float s = 0.f;
            for (int w = 0; w < NWAVE; ++w) s += sRed[w];
            lognormArr[b] = logscale + __logf(s);
        }
    }
}

// ---------------- backtrace ----------------
__global__ __launch_bounds__(64) void backtrace_kernel(const uint16_t* __restrict__ bp,
                                                       const int* __restrict__ seq_len,
                                                       const int* __restrict__ lastArr,
                                                       float* __restrict__ out)
{
    int r = blockIdx.x * 64 + threadIdx.x;
    if (r >= CRF_B) return;
    int L = seq_len[r];
    float* o = out + 1 + (size_t)r * CRF_T;
    int tag = lastArr[r];
    for (int t = CRF_T - 1; t >= L; --t) o[t] = 0.f;
    o[L - 1] = (float)tag;
    for (int t = L - 2; t >= 0; --t) {
        tag = bp[((size_t)r * (CRF_T - 1) + t) * CRF_K + tag];
        o[t] = (float)tag;
    }
}

// ---------------- loss = -mean(score - lognorm) ----------------
__global__ __launch_bounds__(128) void loss_kernel(const float* __restrict__ scoreArr,
                                                   const float* __restrict__ lognormArr,
                                                   float* __restrict__ out)
{
    int tid = threadIdx.x;
    float x = scoreArr[tid] - lognormArr[tid];
    for (int o = 32; o; o >>= 1) x += __shfl_down(x, o);
    __shared__ float r2[2];
    if ((tid & 63) == 0) r2[tid >> 6] = x;
    __syncthreads();
    if (tid == 0) out[0] = -(r2[0] + r2[1]) / (float)CRF_B;
}

extern "C" void kernel_launch(void* const* d_in, const int* in_sizes, int n_in,
                              void* d_out, int out_size, void* d_ws, size_t ws_size,
                              hipStream_t stream)
{
    const float* pot     = (const float*)d_in[0];
    const float* trans   = (const float*)d_in[1];
    const int*   tags    = (const int*)d_in[2];
    const int*   seq_len = (const int*)d_in[3];
    float* out = (float*)d_out;

    char* ws = (char*)d_ws;
    const size_t bpBytes = (size_t)CRF_B * (CRF_T - 1) * CRF_K * 2;      // 39,168,000
    uint16_t* bp   = (uint16_t*)ws;
    uint16_t* expT = (uint16_t*)(ws + bpBytes);                          // 720,000 B
    float* scoreArr   = (float*)(ws + bpBytes + (size_t)CRF_K * CRF_K * 2);
    float* lognormArr = scoreArr + CRF_B;
    int*   lastArr    = (int*)(lognormArr + CRF_B);

    prep_kernel<<<(CRF_K * CRF_K + 255) / 256, 256, 0, stream>>>(trans, expT);
    score_kernel<<<CRF_B, 64, 0, stream>>>(pot, trans, tags, seq_len, scoreArr);
    fwd_kernel<<<2 * CRF_B, FWD_NT, 0, stream>>>(pot, trans, expT, seq_len, bp, lognormArr, lastArr);
    backtrace_kernel<<<(CRF_B + 63) / 64, 64, 0, stream>>>(bp, seq_len, lastArr, out);
    loss_kernel<<<1, 128, 0, stream>>>(scoreArr, lognormArr, out);
}